// Round 8
// baseline (287.490 us; speedup 1.0000x reference)
//
#include <hip/hip_runtime.h>
#include <math.h>

#define NLAYERS 2
#define HID 128
#define FFND 256
#define NH 4
#define SEQL 2048
#define HD 32
#define HDV 64
#define VD 256
#define NBATCH 2
#define MROWS (NBATCH*SEQL)   // 4096
#define NCAT 768              // Q(128) | K(128) | V(256) | G(256)
#define NCHUNK 32             // SEQL / 64

// gammas: 1 - exp(linspace(log(1/32), log(1/512), 4))
#define LG32   (-3.4657359028f)
#define DLT    (-0.9241962407f)   // (log(1/512)-log(1/32))/3
__device__ __forceinline__ float lgamma_h(int h) {
  return logf(1.f - expf(LG32 + DLT * (float)h));
}

// ---------------------------------------------------------------------------
// Kernel A: LN1 + QKVG projection + xPos (inline trig) + decayed KV partials.
// 256 blocks (16-row slabs) x 512 threads. B weights streamed from L2.
// Thread: rows 2ty..2ty+1, f4 col-groups {4tx (Q|K), 256+4tx (V), 512+4tx (G)}.
// ---------------------------------------------------------------------------
__global__ __launch_bounds__(512) void fuse_qkvg(
    const float* __restrict__ X,
    const float* __restrict__ lng, const float* __restrict__ lnb,
    const float* __restrict__ WQ, const float* __restrict__ WK,
    const float* __restrict__ WV, const float* __restrict__ WG,
    float* __restrict__ QKVG, float* __restrict__ Asum4, int l)
{
  __shared__ union {
    float As[128][20];                       // [k][row], LN'd A transposed
    struct { float wK[16][132]; float Vl[16][260]; } kv;  // [t'][col]
  } sm;

  int tid = threadIdx.x;
  int rb = blockIdx.x * 16;
  int ty = tid >> 6;          // 0..7 -> rows 2ty, 2ty+1
  int tx = tid & 63;

  // ---- LN prologue: 32 threads/row, 4 floats each ----
  {
    int row = tid >> 5, q = tid & 31;
    float4 av = *(const float4*)(X + (size_t)(rb + row) * HID + 4*q);
    float s = av.x + av.y + av.z + av.w;
    s += __shfl_xor(s, 1);  s += __shfl_xor(s, 2);
    s += __shfl_xor(s, 4);  s += __shfl_xor(s, 8);  s += __shfl_xor(s, 16);
    float mu = s * (1.f/128.f);
    float dx = av.x-mu, dy = av.y-mu, dz = av.z-mu, dw = av.w-mu;
    float qs = dx*dx + dy*dy + dz*dz + dw*dw;
    qs += __shfl_xor(qs, 1);  qs += __shfl_xor(qs, 2);
    qs += __shfl_xor(qs, 4);  qs += __shfl_xor(qs, 8);  qs += __shfl_xor(qs, 16);
    float rs = rsqrtf(qs * (1.f/128.f) + 1e-5f);
    float4 g4 = *(const float4*)(lng + 4*q);
    float4 b4 = *(const float4*)(lnb + 4*q);
    sm.As[4*q+0][row] = dx*rs*g4.x + b4.x;
    sm.As[4*q+1][row] = dy*rs*g4.y + b4.y;
    sm.As[4*q+2][row] = dz*rs*g4.z + b4.z;
    sm.As[4*q+3][row] = dw*rs*g4.w + b4.w;
  }

  // ---- per-thread B bases ----
  bool isK = (tx >= 32);
  int txk = isK ? (tx - 32) : tx;
  int cq  = 4 * txk;                         // col within Q/K region [0,128)
  const float* b0 = (isK ? WK : WQ) + (size_t)l*NH*HID*HD
                    + (txk >> 3) * (HID*HD) + (cq & 31);
  const float* b1 = WV + (size_t)l*NH*HID*HDV
                    + (tx >> 4) * (HID*HDV) + ((4*tx) & 63);
  const float* b2 = WG + (size_t)l*HID*VD + 4*tx;

  __syncthreads();

  // ---- GEMM: 2 rows x 12 cols, K=128 ----
  float acc[2][12];
  #pragma unroll
  for (int i=0;i<2;i++)
    #pragma unroll
    for (int j=0;j<12;j++) acc[i][j] = 0.f;

  #pragma unroll 4
  for (int k = 0; k < 128; k++) {
    float2 a = *(const float2*)&sm.As[k][2*ty];
    float4 q0 = *(const float4*)(b0 + k*HD);
    float4 v0 = *(const float4*)(b1 + k*HDV);
    float4 g0 = *(const float4*)(b2 + k*VD);
    float bv[12] = { q0.x,q0.y,q0.z,q0.w, v0.x,v0.y,v0.z,v0.w, g0.x,g0.y,g0.z,g0.w };
    float ar[2] = { a.x, a.y };
    #pragma unroll
    for (int i=0;i<2;i++)
      #pragma unroll
      for (int j=0;j<12;j++)
        acc[i][j] = fmaf(ar[i], bv[j], acc[i][j]);
  }

  // ---- xPos rotate on Q/K cols (inline trig) ----
  {
    float sgn = isK ? -1.f : 1.f;
    #pragma unroll
    for (int P = 0; P < 2; P++) {
      float fi   = (float)(((cq & 31) >> 1) + P);
      float invf = exp2f(fi * -0.83048202372f);      // 10000^(-i/16)
      float sv   = (2.f*fi + 12.8f) * (1.f/44.8f);
      float l2sv = log2f(sv) * (1.f/512.f) * sgn;
      #pragma unroll
      for (int i=0;i<2;i++) {
        float s  = (float)((rb & (SEQL-1)) + 2*ty + i);
        float ang = s * invf;
        float sc  = exp2f(l2sv * s);
        float sn = sinf(ang) * sc, cs = cosf(ang) * sc;
        float x1 = acc[i][2*P], x2 = acc[i][2*P+1];
        acc[i][2*P]   = x1*cs - x2*sn;
        acc[i][2*P+1] = x2*cs + x1*sn;
      }
    }
  }

  // ---- store QKVG (Q|K at 4tx, V at 256+4tx, G at 512+4tx) ----
  #pragma unroll
  for (int i=0;i<2;i++) {
    float* cp = QKVG + (size_t)(rb + 2*ty + i) * NCAT;
    float o0[4] = {acc[i][0],acc[i][1],acc[i][2],acc[i][3]};
    float o1[4] = {acc[i][4],acc[i][5],acc[i][6],acc[i][7]};
    float o2[4] = {acc[i][8],acc[i][9],acc[i][10],acc[i][11]};
    *(float4*)(cp + 4*tx)       = *(float4*)o0;
    *(float4*)(cp + 256 + 4*tx) = *(float4*)o1;
    *(float4*)(cp + 512 + 4*tx) = *(float4*)o2;
  }

  __syncthreads();   // As dead; reuse LDS for wK/Vl

  // ---- stage decay-weighted K and V, [t'][col] row-major ----
  if (isK) {
    float lgk = lgamma_h(cq >> 5);
    #pragma unroll
    for (int i=0;i<2;i++) {
      int t = 2*ty + i;
      float w = expf(lgk * (float)(16 - t));
      float o[4] = {acc[i][0]*w, acc[i][1]*w, acc[i][2]*w, acc[i][3]*w};
      *(float4*)&sm.kv.wK[t][cq] = *(float4*)o;
    }
  }
  #pragma unroll
  for (int i=0;i<2;i++) {
    float o[4] = {acc[i][4],acc[i][5],acc[i][6],acc[i][7]};
    *(float4*)&sm.kv.Vl[2*ty+i][4*tx] = *(float4*)o;
  }
  __syncthreads();

  // ---- KV partial: partial[e][v] = sum_t' gamma^(16-t') K[t',e] V[t',v] ----
  {
    int h  = tid >> 7;          // 0..3
    int u  = tid & 127;
    int e2 = u >> 3;            // e = 2*e2 + i
    int v8 = u & 7;             // v = 8*v8 + j
    float pa[2][8];
    #pragma unroll
    for (int i=0;i<2;i++)
      #pragma unroll
      for (int j=0;j<8;j++) pa[i][j] = 0.f;
    #pragma unroll
    for (int t = 0; t < 16; t++) {
      float2 ke = *(const float2*)&sm.kv.wK[t][h*32 + 2*e2];
      float4 va = *(const float4*)&sm.kv.Vl[t][h*64 + 8*v8];
      float4 vb = *(const float4*)&sm.kv.Vl[t][h*64 + 8*v8 + 4];
      float vv[8] = {va.x,va.y,va.z,va.w, vb.x,vb.y,vb.z,vb.w};
      float kk[2] = {ke.x, ke.y};
      #pragma unroll
      for (int i=0;i<2;i++)
        #pragma unroll
        for (int j=0;j<8;j++)
          pa[i][j] = fmaf(kk[i], vv[j], pa[i][j]);
    }
    int b = rb >> 11;
    int c = (rb & (SEQL-1)) >> 6;
    int p = (rb >> 4) & 3;
    float scale = expf(lgamma_h(h) * (float)(48 - 16*p));
    float* ob = Asum4 + ((size_t)((b*NH + h)*NCHUNK + c)*4 + p)*2048
                + (2*e2)*64 + 8*v8;
    #pragma unroll
    for (int i=0;i<2;i++) {
      float o0[4] = {pa[i][0]*scale, pa[i][1]*scale, pa[i][2]*scale, pa[i][3]*scale};
      float o1[4] = {pa[i][4]*scale, pa[i][5]*scale, pa[i][6]*scale, pa[i][7]*scale};
      *(float4*)(ob + i*64)     = *(float4*)o0;
      *(float4*)(ob + i*64 + 4) = *(float4*)o1;
    }
  }
}

// ---------------------------------------------------------------------------
// Kernel B: retention output + GroupNorm + SiLU gate (proven structure).
// Scan reads 4 sub-chunk partials per chunk from Asum4.
// ---------------------------------------------------------------------------
__global__ __launch_bounds__(512) void ret_out_kernel(
    const float* __restrict__ QKVG, const float* __restrict__ Asum4,
    const float* __restrict__ gn_g, const float* __restrict__ gn_b,
    float* __restrict__ Gated)
{
  int bh = blockIdx.x >> 5;
  int c  = blockIdx.x & 31;
  int b = bh >> 2, h = bh & 3;
  float lg = lgamma_h(h);
  float g64 = __expf(lg * 64.f);

  __shared__ float Qs[64][36];
  __shared__ float Ks[64][36];
  __shared__ float Vs[64][68];
  __shared__ float Ss[64][68];
  __shared__ float Sc[32][68];

  int tid = threadIdx.x;
  int tx2 = tid & 31, ty2 = tid >> 5;   // cols 2*tx2, rows 4*ty2
  int c0 = c * 64;
  const float* base = QKVG + (size_t)(b * SEQL) * NCAT;

  {
    int row = tid >> 3, eq = tid & 7;
    *(float4*)&Qs[row][4*eq] =
        *(const float4*)(base + (size_t)(c0+row)*NCAT + h*32 + 4*eq);
    int esw = (4*eq) ^ (4*((row >> 2) & 7));
    *(float4*)&Ks[row][esw] =
        *(const float4*)(base + (size_t)(c0+row)*NCAT + 128 + h*32 + 4*eq);
  }
  #pragma unroll
  for (int it = 0; it < 2; it++) {
    int idx = it*512 + tid;
    int row = idx >> 4, vq = idx & 15;
    *(float4*)&Vs[row][4*vq] =
        *(const float4*)(base + (size_t)(c0+row)*NCAT + 256 + h*64 + 4*vq);
  }

  {                                           // cross-chunk scan over partials
    int e = tid >> 4, v4 = (tid & 15) * 4;
    float s0[4] = {0,0,0,0};
    float w = 1.f;
    const float* ab = Asum4 + ((size_t)bh*NCHUNK*4)*2048 + e*64 + v4;
    for (int cp = c-1; cp >= 0; --cp) {
      const float* ap = ab + (size_t)cp*4*2048;
      float4 x0 = *(const float4*)ap;
      float4 x1 = *(const float4*)(ap + 2048);
      float4 x2 = *(const float4*)(ap + 4096);
      float4 x3 = *(const float4*)(ap + 6144);
      float sx = x0.x+x1.x+x2.x+x3.x, sy = x0.y+x1.y+x2.y+x3.y;
      float sz = x0.z+x1.z+x2.z+x3.z, sw = x0.w+x1.w+x2.w+x3.w;
      s0[0] = fmaf(w, sx, s0[0]); s0[1] = fmaf(w, sy, s0[1]);
      s0[2] = fmaf(w, sz, s0[2]); s0[3] = fmaf(w, sw, s0[3]);
      w *= g64;
    }
    *(float4*)&Sc[e][v4] = *(float4*)s0;
  }
  __syncthreads();

  // intra-chunk S = Q K^T (.) decay -> Ss
  float sacc[4][2];
  #pragma unroll
  for (int i=0;i<4;i++) { sacc[i][0]=0.f; sacc[i][1]=0.f; }
  #pragma unroll
  for (int e = 0; e < 32; e += 4) {
    float qv[4][4], kv[2][4];
    #pragma unroll
    for (int i=0;i<4;i++)
      *(float4*)qv[i] = *(const float4*)&Qs[4*ty2+i][e];
    #pragma unroll
    for (int j=0;j<2;j++) {
      int kr = 2*tx2 + j;
      *(float4*)kv[j] = *(const float4*)&Ks[kr][e ^ (4*((kr>>2)&7))];
    }
    #pragma unroll
    for (int i=0;i<4;i++)
      #pragma unroll
      for (int j=0;j<2;j++)
        sacc[i][j] = fmaf(qv[i][0], kv[j][0],
                     fmaf(qv[i][1], kv[j][1],
                     fmaf(qv[i][2], kv[j][2],
                     fmaf(qv[i][3], kv[j][3], sacc[i][j]))));
  }
  #pragma unroll
  for (int i=0;i<4;i++) {
    int sl = 4*ty2 + i;
    float o2[2];
    #pragma unroll
    for (int j=0;j<2;j++) {
      int dr = sl - (2*tx2 + j);
      float w = (dr >= 0) ? __expf(lg * (float)dr) : 0.f;
      o2[j] = sacc[i][j] * w;
    }
    *(float2*)&Ss[sl][2*tx2] = *(float2*)o2;
  }

  // cross term: acc = diag(gamma^sl) * (Q @ Sc)
  float acc[4][2];
  #pragma unroll
  for (int i=0;i<4;i++) { acc[i][0]=0.f; acc[i][1]=0.f; }
  #pragma unroll
  for (int e = 0; e < 32; e += 4) {
    float qv[4][4], sv[4][2];
    #pragma unroll
    for (int i=0;i<4;i++)
      *(float4*)qv[i] = *(const float4*)&Qs[4*ty2+i][e];
    #pragma unroll
    for (int m=0;m<4;m++)
      *(float2*)sv[m] = *(const float2*)&Sc[e+m][2*tx2];
    #pragma unroll
    for (int i=0;i<4;i++)
      #pragma unroll
      for (int j=0;j<2;j++)
        acc[i][j] = fmaf(qv[i][0], sv[0][j],
                    fmaf(qv[i][1], sv[1][j],
                    fmaf(qv[i][2], sv[2][j],
                    fmaf(qv[i][3], sv[3][j], acc[i][j]))));
  }
  #pragma unroll
  for (int i=0;i<4;i++) {
    float gr = __expf(lg * (float)(4*ty2 + i));
    acc[i][0] *= gr; acc[i][1] *= gr;
  }
  __syncthreads();

  // Y += Ss @ V
  #pragma unroll
  for (int t = 0; t < 64; t += 4) {
    float sv[4][4], vv[4][2];
    #pragma unroll
    for (int i=0;i<4;i++)
      *(float4*)sv[i] = *(const float4*)&Ss[4*ty2+i][t];
    #pragma unroll
    for (int m=0;m<4;m++)
      *(float2*)vv[m] = *(const float2*)&Vs[t+m][2*tx2];
    #pragma unroll
    for (int i=0;i<4;i++)
      #pragma unroll
      for (int j=0;j<2;j++)
        acc[i][j] = fmaf(sv[i][0], vv[0][j],
                    fmaf(sv[i][1], vv[1][j],
                    fmaf(sv[i][2], vv[2][j],
                    fmaf(sv[i][3], vv[3][j], acc[i][j]))));
  }

  // GroupNorm (per head over 64 cols / 32 lanes) + SiLU gate
  #pragma unroll
  for (int i=0;i<4;i++) {
    float s1 = acc[i][0] + acc[i][1];
    #pragma unroll
    for (int o = 16; o; o >>= 1) s1 += __shfl_xor(s1, o);
    float mu = s1 * (1.f/64.f);
    float q = 0.f;
    #pragma unroll
    for (int j=0;j<2;j++) { float d = acc[i][j] - mu; q += d*d; }
    #pragma unroll
    for (int o = 16; o; o >>= 1) q += __shfl_xor(q, o);
    float rs = rsqrtf(q * (1.f/64.f) + 1e-5f);
    int row = b*SEQL + c0 + 4*ty2 + i;
    float2 g2 = *(const float2*)(QKVG + (size_t)row*NCAT + 512 + h*64 + 2*tx2);
    float gv[2] = {g2.x, g2.y};
    float o2[2];
    #pragma unroll
    for (int j=0;j<2;j++) {
      int col = h*64 + 2*tx2 + j;
      float yn = (acc[i][j] - mu) * rs * gn_g[col] + gn_b[col];
      float g = gv[j];
      float sig = 1.f / (1.f + __expf(-g));
      o2[j] = g * sig * yn;
    }
    *(float2*)(Gated + (size_t)row*VD + h*64 + 2*tx2) = *(float2*)o2;
  }
}

// ---------------------------------------------------------------------------
// Kernel C: WO + residual + LN2 + FFN1(gelu) + FFN2 + residual, one kernel.
// 256 blocks (16-row slabs) x 512 threads. Yres/h2/Mid never hit global.
// ---------------------------------------------------------------------------
__global__ __launch_bounds__(512) void fuse_ffn(
    const float* __restrict__ Gated, const float* __restrict__ WO,
    const float* __restrict__ Xres,
    const float* __restrict__ lng, const float* __restrict__ lnb,
    const float* __restrict__ w1, const float* __restrict__ b1,
    const float* __restrict__ w2, const float* __restrict__ b2,
    float* __restrict__ Out)
{
  __shared__ float bufA[256][20];   // Gs (WO stage), then Ms (Mid, transposed)
  __shared__ float h2s[128][20];
  __shared__ float Ys[16][130];

  int tid = threadIdx.x;
  int rb = blockIdx.x * 16;
  int ty = tid >> 6;          // rows 2ty, 2ty+1
  int tx = tid & 63;

  // ---- stage Gated transposed: bufA[k][row] ----
  {
    int row = tid >> 5, q = tid & 31;
    const float* gr = Gated + (size_t)(rb + row) * VD + 8*q;
    float4 a0 = *(const float4*)gr;
    float4 a1 = *(const float4*)(gr + 4);
    bufA[8*q+0][row] = a0.x; bufA[8*q+1][row] = a0.y;
    bufA[8*q+2][row] = a0.z; bufA[8*q+3][row] = a0.w;
    bufA[8*q+4][row] = a1.x; bufA[8*q+5][row] = a1.y;
    bufA[8*q+6][row] = a1.z; bufA[8*q+7][row] = a1.w;
  }
  __syncthreads();

  // ---- WO: 2 rows x 2 cols, K=256 ----
  float yr[2][2];
  {
    float acc[2][2] = {{0.f,0.f},{0.f,0.f}};
    #pragma unroll 8
    for (int k = 0; k < 256; k++) {
      float2 a = *(const float2*)&bufA[k][2*ty];
      float2 bb = *(const float2*)(WO + (size_t)k*HID + 2*tx);
      acc[0][0] = fmaf(a.x, bb.x, acc[0][0]);
      acc[0][1] = fmaf(a.x, bb.y, acc[0][1]);
      acc[1][0] = fmaf(a.y, bb.x, acc[1][0]);
      acc[1][1] = fmaf(a.y, bb.y, acc[1][1]);
    }
    #pragma unroll
    for (int i=0;i<2;i++) {
      float2 xr = *(const float2*)(Xres + (size_t)(rb + 2*ty + i)*HID + 2*tx);
      yr[i][0] = acc[i][0] + xr.x;
      yr[i][1] = acc[i][1] + xr.y;
    }
  }

  // ---- LN2 (wave = 2 rows x 128 cols) + stage h2s, Ys ----
  #pragma unroll
  for (int i=0;i<2;i++) {
    float s = yr[i][0] + yr[i][1];
    #pragma unroll
    for (int o = 32; o; o >>= 1) s += __shfl_xor(s, o);
    float mu = s * (1.f/128.f);
    float d0 = yr[i][0]-mu, d1 = yr[i][1]-mu;
    float q = d0*d0 + d1*d1;
    #pragma unroll
    for (int o = 32; o; o >>= 1) q += __shfl_xor(q, o);
    float rs = rsqrtf(q * (1.f/128.f) + 1e-5f);
    h2s[2*tx+0][2*ty+i] = d0*rs*lng[2*tx+0] + lnb[2*tx+0];
    h2s[2*tx+1][2*ty+i] = d1*rs*lng[2*tx+1] + lnb[2*tx+1];
    float o2[2] = {yr[i][0], yr[i][1]};
    *(float2*)&Ys[2*ty+i][2*tx] = *(float2*)o2;
  }
  __syncthreads();   // h2s ready; bufA (Gs) reads done -> reusable

  // ---- FFN1: 2 rows x 4 cols, K=128; gelu; Mid -> bufA transposed ----
  {
    float acc[2][4];
    #pragma unroll
    for (int i=0;i<2;i++)
      #pragma unroll
      for (int j=0;j<4;j++) acc[i][j] = 0.f;
    #pragma unroll 8
    for (int k = 0; k < 128; k++) {
      float2 a = *(const float2*)&h2s[k][2*ty];
      float4 bb = *(const float4*)(w1 + (size_t)k*FFND + 4*tx);
      float bv[4] = {bb.x,bb.y,bb.z,bb.w};
      #pragma unroll
      for (int j=0;j<4;j++) {
        acc[0][j] = fmaf(a.x, bv[j], acc[0][j]);
        acc[1][j] = fmaf(a.y, bv[j], acc[1][j]);
      }
    }
    float4 bi = *(const float4*)(b1 + 4*tx);
    float bvi[4] = {bi.x,bi.y,bi.z,bi.w};
    #pragma unroll
    for (int i=0;i<2;i++)
      #pragma unroll
      for (int j=0;j<4;j++) {
        float v = acc[i][j] + bvi[j];
        bufA[4*tx+j][2*ty+i] = 0.5f * v * (1.f + erff(v * 0.70710678118f));
      }
  }
  __syncthreads();

  // ---- FFN2: 2 rows x 2 cols, K=256; + b2 + Yres -> Out ----
  {
    float acc[2][2] = {{0.f,0.f},{0.f,0.f}};
    #pragma unroll 8
    for (int k = 0; k < 256; k++) {
      float2 a = *(const float2*)&bufA[k][2*ty];
      float2 bb = *(const float2*)(w2 + (size_t)k*HID + 2*tx);
      acc[0][0] = fmaf(a.x, bb.x, acc[0][0]);
      acc[0][1] = fmaf(a.x, bb.y, acc[0][1]);
      acc[1][0] = fmaf(a.y, bb.x, acc[1][0]);
      acc[1][1] = fmaf(a.y, bb.y, acc[1][1]);
    }
    #pragma unroll
    for (int i=0;i<2;i++) {
      float2 yv = *(const float2*)&Ys[2*ty+i][2*tx];
      float o2[2] = { acc[i][0] + b2[2*tx+0] + yv.x,
                      acc[i][1] + b2[2*tx+1] + yv.y };
      *(float2*)(Out + (size_t)(rb + 2*ty + i)*HID + 2*tx) = *(float2*)o2;
    }
  }
}

// ---------------------------------------------------------------------------
extern "C" void kernel_launch(void* const* d_in, const int* in_sizes, int n_in,
                              void* d_out, int out_size, void* d_ws, size_t ws_size,
                              hipStream_t stream)
{
  (void)in_sizes; (void)n_in; (void)out_size; (void)ws_size;
  const float* x_in  = (const float*)d_in[0];
  const float* ln1_g = (const float*)d_in[1];
  const float* ln1_b = (const float*)d_in[2];
  const float* ln2_g = (const float*)d_in[3];
  const float* ln2_b = (const float*)d_in[4];
  const float* WQ    = (const float*)d_in[5];
  const float* WK    = (const float*)d_in[6];
  const float* WV    = (const float*)d_in[7];
  const float* WG    = (const float*)d_in[8];
  const float* WO    = (const float*)d_in[9];
  const float* gn_g  = (const float*)d_in[10];
  const float* gn_b  = (const float*)d_in[11];
  const float* w1    = (const float*)d_in[12];
  const float* b1    = (const float*)d_in[13];
  const float* w2    = (const float*)d_in[14];
  const float* b2    = (const float*)d_in[15];
  float* out = (float*)d_out;
  float* ws  = (float*)d_ws;

  float* QKVG  = ws;                      // 3145728
  float* Asum4 = QKVG + 3145728;          // 2097152 (8 bh x 32 c x 4 p x 2048)
  float* Gt    = Asum4 + 2097152;         // 1048576

  for (int l = 0; l < NLAYERS; l++) {
    const float* xl = (l == 0) ? x_in : out;
    fuse_qkvg<<<256, 512, 0, stream>>>(
        xl, ln1_g + l*HID, ln1_b + l*HID, WQ, WK, WV, WG, QKVG, Asum4, l);
    ret_out_kernel<<<256, 512, 0, stream>>>(
        QKVG, Asum4, gn_g + l*VD, gn_b + l*VD, Gt);
    fuse_ffn<<<256, 512, 0, stream>>>(
        Gt, WO + l*VD*HID, xl, ln2_g + l*HID, ln2_b + l*HID,
        w1 + l*HID*FFND, b1 + l*FFND, w2 + l*FFND*HID, b2 + l*HID, out);
  }
}